// Round 1
// baseline (733.889 us; speedup 1.0000x reference)
//
#include <hip/hip_runtime.h>
#include <hip/hip_bf16.h>
#include <math.h>

// Problem constants
#define BGR  256      // graphs
#define NN   400      // nodes per graph (stage 1)
#define EPG  6400     // edges per graph
#define HDIM 64

// ---------------------------------------------------------------------------
// GEMM: H[M x 64] = X[M x K] @ W[K x 64], M multiple of 64, f32.
// Block: 256 threads computes a 64-row tile. thread: col c = tid&63,
// 16 rows (mg..mg+15). xs tile in LDS, broadcast b128 reads over k.
// ---------------------------------------------------------------------------
template<int K>
__global__ __launch_bounds__(256) void gemm64(const float* __restrict__ X,
                                              const float* __restrict__ W,
                                              float* __restrict__ H) {
  __shared__ float xs[64][K + 8];   // row stride K+8 floats -> 16B aligned rows
  const int m0 = blockIdx.x * 64;
  // cooperative tile load, float4
  for (int i = threadIdx.x; i < 64 * (K / 4); i += 256) {
    int m = i / (K / 4), q = i % (K / 4);
    float4 v = *reinterpret_cast<const float4*>(X + (size_t)(m0 + m) * K + q * 4);
    *reinterpret_cast<float4*>(&xs[m][q * 4]) = v;
  }
  __syncthreads();
  const int c = threadIdx.x & 63;
  const int mg = (threadIdx.x >> 6) * 16;
  float acc[16];
#pragma unroll
  for (int i = 0; i < 16; ++i) acc[i] = 0.f;
  for (int k = 0; k < K; k += 4) {
    float w0 = W[(k + 0) * 64 + c];
    float w1 = W[(k + 1) * 64 + c];
    float w2 = W[(k + 2) * 64 + c];
    float w3 = W[(k + 3) * 64 + c];
#pragma unroll
    for (int i = 0; i < 16; ++i) {
      float4 xv = *reinterpret_cast<const float4*>(&xs[mg + i][k]);
      float a = acc[i];
      a = fmaf(xv.x, w0, a);
      a = fmaf(xv.y, w1, a);
      a = fmaf(xv.z, w2, a);
      a = fmaf(xv.w, w3, a);
      acc[i] = a;
    }
  }
#pragma unroll
  for (int i = 0; i < 16; ++i)
    H[(size_t)(m0 + mg + i) * 64 + c] = acc[i];
}

// ---------------------------------------------------------------------------
// GCN conv, one block per graph. In-place on h (pre -> post, relu applied).
// LEVEL: 0 = all edges valid (stage1), 1 = via nmap1, 2 = via nmap1->nmap2.
// COMPACT: build LDS list of valid local edges first (stages 2,3).
// NCH: channels per LDS pass (32 for stage1 to fit 64KB, else 64).
// RSUM: also emit per-graph column sums of the output (stage 3 fuse).
// ---------------------------------------------------------------------------
template<int NPER, int LEVEL, bool COMPACT, bool RSUM, int NCH>
__global__ __launch_bounds__(512) void gcn_conv_k(
    float* __restrict__ h,
    const int* __restrict__ src, const int* __restrict__ dst,
    const int* __restrict__ nmap1, const int* __restrict__ nmap2,
    const float* __restrict__ bias, float* __restrict__ rsum) {
  constexpr int HALVES = 64 / NCH;
  __shared__ float agg[NPER * NCH];
  __shared__ float dinv[NPER];
  __shared__ float recip[NPER];
  __shared__ int   deg[NPER];
  __shared__ int   cnt[1];
  __shared__ int   elist[COMPACT ? EPG : 1];
  __shared__ float rs[RSUM ? 64 : 1];

  const int g = blockIdx.x;
  const int tid = threadIdx.x;
  const int lane = tid & 63, wave = tid >> 6;
  const int e0 = g * EPG;
  const size_t hbase = (size_t)g * NPER * 64;

  for (int i = tid; i < NPER; i += 512) deg[i] = 0;
  if (COMPACT && tid == 0) cnt[0] = 0;
  if (RSUM && tid < 64) rs[tid] = 0.f;
  __syncthreads();

  // ---- degree (+ optional compaction of valid local edges) ----
  for (int e = tid; e < EPG; e += 512) {
    int s = src[e0 + e], d = dst[e0 + e];
    int ls = 0, ld = 0; bool valid = true;
    if (LEVEL == 0) {
      ls = s - g * NPER; ld = d - g * NPER;
    } else if (LEVEL == 1) {
      int ns = nmap1[s], nd = nmap1[d];
      valid = (ns >= 0) && (nd >= 0);
      ls = ns - g * NPER; ld = nd - g * NPER;
    } else {
      int ns = nmap1[s], nd = nmap1[d];
      if (ns >= 0 && nd >= 0) {
        int ns2 = nmap2[ns], nd2 = nmap2[nd];
        valid = (ns2 >= 0) && (nd2 >= 0);
        ls = ns2 - g * NPER; ld = nd2 - g * NPER;
      } else {
        valid = false;
      }
    }
    if (valid) {
      atomicAdd(&deg[ld], 1);
      if (COMPACT) { int p = atomicAdd(&cnt[0], 1); elist[p] = ls | (ld << 16); }
    }
  }
  __syncthreads();
  for (int i = tid; i < NPER; i += 512) {
    float df = (float)deg[i] + 1.0f;
    dinv[i]  = 1.0f / sqrtf(df);
    recip[i] = 1.0f / df;
  }
  __syncthreads();

  float part = 0.f;
  for (int half = 0; half < HALVES; ++half) {
    for (int i = tid; i < NPER * NCH; i += 512) agg[i] = 0.f;
    __syncthreads();

    if (COMPACT) {
      // NCH == 64 here: lane = channel, one edge per wave-iter
      const int n = cnt[0];
      for (int i = wave; i < n; i += 8) {
        int pk = elist[i];
        int ls = pk & 0xFFFF, ld = pk >> 16;
        float coef = dinv[ls] * dinv[ld];
        float v = coef * h[hbase + (size_t)ls * 64 + lane];
        atomicAdd(&agg[ld * 64 + lane], v);
      }
    } else {
      // stage 1: NCH == 32, two edges per wave (lane halves), unroll 8
      const int ch = lane & 31, sub = lane >> 5;
      const int cofs = half * 32 + ch;
      for (int i2 = wave * 8; i2 < EPG / 2; i2 += 64) {
        float v[8]; int ldq[8];
#pragma unroll
        for (int q = 0; q < 8; ++q) {
          int e = e0 + 2 * (i2 + q) + sub;
          int s = src[e], d = dst[e];
          int ls = s - g * NPER;
          ldq[q] = d - g * NPER;
          v[q] = dinv[ls] * h[hbase + (size_t)ls * 64 + cofs];
        }
#pragma unroll
        for (int q = 0; q < 8; ++q)
          atomicAdd(&agg[ldq[q] * 32 + ch], dinv[ldq[q]] * v[q]);
      }
    }
    __syncthreads();

    // ---- epilogue for this half: out = relu(agg + h/deg + b) ----
    for (int idx = tid; idx < NPER * NCH; idx += 512) {
      int i  = idx / NCH;
      int ch = idx & (NCH - 1);
      int col = half * NCH + ch;
      size_t a = hbase + (size_t)i * 64 + col;
      float u = h[a];
      float o = agg[idx] + u * recip[i] + bias[col];
      o = fmaxf(o, 0.f);
      h[a] = o;
      if (RSUM) part += o;
    }
    __syncthreads();
  }

  if (RSUM) {
    atomicAdd(&rs[tid & 63], part);   // thread's column is constant (NCH==64)
    __syncthreads();
    if (tid < 64) rsum[g * 64 + tid] = rs[tid];
  }
}

// ---------------------------------------------------------------------------
// TopK pooling, one block per graph. score = tanh(h.pw/||pw||),
// stable rank selection (exact lax.top_k semantics), writes pooled rows
// (xp = h[sel]*score[sel]), nmap (old->new or -1) and per-graph sum (r).
// ---------------------------------------------------------------------------
template<int NPER, int KK>
__global__ __launch_bounds__(512) void topk_pool_k(
    const float* __restrict__ h, const float* __restrict__ pw,
    float* __restrict__ xp, int* __restrict__ nmap, float* __restrict__ rsum) {
  __shared__ float sc[NPER];
  __shared__ int   sel[KK];
  __shared__ float rs[64];
  const int g = blockIdx.x, tid = threadIdx.x;
  const int lane = tid & 63, wave = tid >> 6;
  const size_t base = (size_t)g * NPER * 64;

  float pwl = pw[lane];
  float t = pwl * pwl;
#pragma unroll
  for (int o = 32; o; o >>= 1) t += __shfl_xor(t, o);
  const float nrm = sqrtf(t);

  for (int i = wave; i < NPER; i += 8) {
    float d = h[base + (size_t)i * 64 + lane] * pwl;
#pragma unroll
    for (int o = 32; o; o >>= 1) d += __shfl_xor(d, o);
    if (lane == 0) sc[i] = tanhf(d / nrm);
  }
  if (tid < 64) rs[tid] = 0.f;
  __syncthreads();

  if (tid < NPER) {
    float si = sc[tid];
    int r = 0;
    for (int j = 0; j < NPER; ++j) {
      float sj = sc[j];
      r += (sj > si) || (sj == si && j < tid);
    }
    nmap[g * NPER + tid] = (r < KK) ? (g * KK + r) : -1;
    if (r < KK) sel[r] = tid;
  }
  __syncthreads();

  float part = 0.f;
  for (int r = wave; r < KK; r += 8) {
    int i = sel[r];
    float s = sc[i];
    float v = h[base + (size_t)i * 64 + lane] * s;
    xp[((size_t)g * KK + r) * 64 + lane] = v;
    part += v;
  }
  atomicAdd(&rs[lane], part);
  __syncthreads();
  if (tid < 64) rsum[g * 64 + tid] = rs[tid];
}

// ---------------------------------------------------------------------------
// Final linear: out[g] = [r3|r2|r1] @ Wl + bl   (256 x 192 @ 192 x 2)
// ---------------------------------------------------------------------------
__global__ __launch_bounds__(256) void final_linear(
    const float* __restrict__ r3, const float* __restrict__ r2,
    const float* __restrict__ r1, const float* __restrict__ Wl,
    const float* __restrict__ bl, float* __restrict__ out) {
  int g = threadIdx.x;
  if (g >= BGR) return;
  float a0 = bl[0], a1 = bl[1];
  for (int t = 0; t < 64; ++t) {
    float v = r3[g * 64 + t];
    a0 = fmaf(v, Wl[t * 2 + 0], a0);
    a1 = fmaf(v, Wl[t * 2 + 1], a1);
  }
  for (int t = 0; t < 64; ++t) {
    float v = r2[g * 64 + t];
    a0 = fmaf(v, Wl[(64 + t) * 2 + 0], a0);
    a1 = fmaf(v, Wl[(64 + t) * 2 + 1], a1);
  }
  for (int t = 0; t < 64; ++t) {
    float v = r1[g * 64 + t];
    a0 = fmaf(v, Wl[(128 + t) * 2 + 0], a0);
    a1 = fmaf(v, Wl[(128 + t) * 2 + 1], a1);
  }
  out[g * 2 + 0] = a0;
  out[g * 2 + 1] = a1;
}

// ---------------------------------------------------------------------------
extern "C" void kernel_launch(void* const* d_in, const int* in_sizes, int n_in,
                              void* d_out, int out_size, void* d_ws, size_t ws_size,
                              hipStream_t stream) {
  const float* x   = (const float*)d_in[0];
  const int*   src = (const int*)d_in[1];
  const int*   dst = (const int*)d_in[2];
  // d_in[3] = batch (unused)
  const float* W1  = (const float*)d_in[4];
  const float* b1  = (const float*)d_in[5];
  const float* W2  = (const float*)d_in[6];
  const float* b2  = (const float*)d_in[7];
  const float* W3  = (const float*)d_in[8];
  const float* b3  = (const float*)d_in[9];
  const float* pw1 = (const float*)d_in[10];
  const float* pw2 = (const float*)d_in[11];
  const float* Wl  = (const float*)d_in[12];
  const float* bl  = (const float*)d_in[13];
  float* out = (float*)d_out;

  // workspace layout (floats). h2/hp2/h3 alias h1 (dead after topk1).
  float* ws    = (float*)d_ws;
  float* h1    = ws;                               // 102400*64 = 6,553,600
  float* hp1   = h1 + (size_t)102400 * 64;         // 25600*64  = 1,638,400
  int*   nmap1 = (int*)(hp1 + (size_t)25600 * 64); // 102,400
  int*   nmap2 = nmap1 + 102400;                   // 25,600
  float* r1    = (float*)(nmap2 + 25600);          // 16,384
  float* r2    = r1 + 16384;
  float* r3    = r2 + 16384;
  float* h2    = h1;                               // alias: 25600*64
  float* hp2   = h1 + (size_t)25600 * 64;          // alias: 6400*64
  float* h3    = h1 + (size_t)2 * 25600 * 64 - (size_t)25600 * 64 + (size_t)25600 * 64; // see below
  h3 = h1 + (size_t)25600 * 64 + (size_t)6400 * 64; // after h2 and hp2 regions

  // Stage 1
  gemm64<128><<<102400 / 64, 256, 0, stream>>>(x, W1, h1);
  gcn_conv_k<400, 0, false, false, 32><<<BGR, 512, 0, stream>>>(
      h1, src, dst, nullptr, nullptr, b1, nullptr);
  topk_pool_k<400, 100><<<BGR, 512, 0, stream>>>(h1, pw1, hp1, nmap1, r1);

  // Stage 2
  gemm64<64><<<25600 / 64, 256, 0, stream>>>(hp1, W2, h2);
  gcn_conv_k<100, 1, true, false, 64><<<BGR, 512, 0, stream>>>(
      h2, src, dst, nmap1, nullptr, b2, nullptr);
  topk_pool_k<100, 25><<<BGR, 512, 0, stream>>>(h2, pw2, hp2, nmap2, r2);

  // Stage 3
  gemm64<64><<<6400 / 64, 256, 0, stream>>>(hp2, W3, h3);
  gcn_conv_k<25, 2, true, true, 64><<<BGR, 512, 0, stream>>>(
      h3, src, dst, nmap1, nmap2, b3, r3);

  // Readout
  final_linear<<<1, 256, 0, stream>>>(r3, r2, r1, Wl, bl, out);
}

// Round 2
// 289.080 us; speedup vs baseline: 2.5387x; 2.5387x over previous
//
#include <hip/hip_runtime.h>
#include <hip/hip_bf16.h>
#include <math.h>

// Problem constants
#define BGR  256      // graphs
#define NN   400      // nodes per graph (stage 1)
#define EPG  6400     // edges per graph
#define HDIM 64

// ---------------------------------------------------------------------------
// GEMM: H[M x 64] = X[M x K] @ W[K x 64], M multiple of 64, f32.
// ---------------------------------------------------------------------------
template<int K>
__global__ __launch_bounds__(256) void gemm64(const float* __restrict__ X,
                                              const float* __restrict__ W,
                                              float* __restrict__ H) {
  __shared__ float xs[64][K + 8];
  const int m0 = blockIdx.x * 64;
  for (int i = threadIdx.x; i < 64 * (K / 4); i += 256) {
    int m = i / (K / 4), q = i % (K / 4);
    float4 v = *reinterpret_cast<const float4*>(X + (size_t)(m0 + m) * K + q * 4);
    *reinterpret_cast<float4*>(&xs[m][q * 4]) = v;
  }
  __syncthreads();
  const int c = threadIdx.x & 63;
  const int mg = (threadIdx.x >> 6) * 16;
  float acc[16];
#pragma unroll
  for (int i = 0; i < 16; ++i) acc[i] = 0.f;
  for (int k = 0; k < K; k += 4) {
    float w0 = W[(k + 0) * 64 + c];
    float w1 = W[(k + 1) * 64 + c];
    float w2 = W[(k + 2) * 64 + c];
    float w3 = W[(k + 3) * 64 + c];
#pragma unroll
    for (int i = 0; i < 16; ++i) {
      float4 xv = *reinterpret_cast<const float4*>(&xs[mg + i][k]);
      float a = acc[i];
      a = fmaf(xv.x, w0, a);
      a = fmaf(xv.y, w1, a);
      a = fmaf(xv.z, w2, a);
      a = fmaf(xv.w, w3, a);
      acc[i] = a;
    }
  }
#pragma unroll
  for (int i = 0; i < 16; ++i)
    H[(size_t)(m0 + mg + i) * 64 + c] = acc[i];
}

// ---------------------------------------------------------------------------
// Stage-1 GCN conv: CSR gather-reduce, register accumulation, no float
// atomics. Grid: (4, BGR). Block (q, g) owns channels [q*16, q*16+16) of
// graph g and updates h in place (disjoint columns across blocks; within
// a block outputs are register-buffered until all reads are done).
// ---------------------------------------------------------------------------
__global__ __launch_bounds__(512) void gcn_conv1_csr(
    float* __restrict__ h,
    const int* __restrict__ src, const int* __restrict__ dst,
    const float* __restrict__ bias) {
  __shared__ int            deg[NN];
  __shared__ float          dinv[NN];
  __shared__ float          recip[NN];
  __shared__ int            off[NN];
  __shared__ int            cur[NN];
  __shared__ unsigned short csr[EPG];

  const int q = blockIdx.x, g = blockIdx.y;
  const int tid = threadIdx.x;
  const int e0 = g * EPG;
  const size_t hbase = (size_t)g * NN * 64;

  for (int i = tid; i < NN; i += 512) deg[i] = 0;
  __syncthreads();

  // degree
  for (int e = tid; e < EPG; e += 512) {
    int ld = dst[e0 + e] - g * NN;
    atomicAdd(&deg[ld], 1);
  }
  __syncthreads();

  for (int i = tid; i < NN; i += 512) {
    float df = (float)deg[i] + 1.0f;
    dinv[i]  = 1.0f / sqrtf(df);
    recip[i] = 1.0f / df;
  }
  // prefix sum of deg -> off (broadcast loop, threads 0..NN-1)
  if (tid < NN) {
    int s = 0;
    for (int j = 0; j < NN; ++j) {
      int d = deg[j];
      if (j < tid) s += d;
    }
    off[tid] = s;
    cur[tid] = s;
  }
  __syncthreads();

  // fill CSR (sorted by dst), entries are local src ids
  for (int e = tid; e < EPG; e += 512) {
    int ls = src[e0 + e] - g * NN;
    int ld = dst[e0 + e] - g * NN;
    int p = atomicAdd(&cur[ld], 1);
    csr[p] = (unsigned short)ls;
  }
  __syncthreads();

  // gather-reduce: 16-lane group per dst node, lane = channel within quarter
  const int lane = tid & 63, wave = tid >> 6;
  const int grp = (lane >> 4) & 3;        // 0..3
  const int l16 = lane & 15;              // 0..15
  const int col = q * 16 + l16;
  const float bcol = bias[col];

  float outv[13];
#pragma unroll
  for (int it = 0; it < 13; ++it) {
    int n = it * 32 + wave * 4 + grp;
    float r = 0.f;
    if (n < NN) {
      int b = off[n], cnt = deg[n], end = b + cnt;
      float a0 = 0.f, a1 = 0.f, a2 = 0.f, a3 = 0.f;
      float hn = h[hbase + (size_t)n * 64 + col];
      int e = b;
      for (; e + 3 < end; e += 4) {
        int s0 = csr[e], s1 = csr[e + 1], s2 = csr[e + 2], s3 = csr[e + 3];
        a0 += dinv[s0] * h[hbase + (size_t)s0 * 64 + col];
        a1 += dinv[s1] * h[hbase + (size_t)s1 * 64 + col];
        a2 += dinv[s2] * h[hbase + (size_t)s2 * 64 + col];
        a3 += dinv[s3] * h[hbase + (size_t)s3 * 64 + col];
      }
      for (; e < end; ++e) {
        int s0 = csr[e];
        a0 += dinv[s0] * h[hbase + (size_t)s0 * 64 + col];
      }
      r = ((a0 + a1) + (a2 + a3)) * dinv[n] + hn * recip[n] + bcol;
      r = fmaxf(r, 0.f);
    }
    outv[it] = r;
  }
  __syncthreads();   // all reads of h complete before any write
#pragma unroll
  for (int it = 0; it < 13; ++it) {
    int n = it * 32 + wave * 4 + grp;
    if (n < NN) h[hbase + (size_t)n * 64 + col] = outv[it];
  }
}

// ---------------------------------------------------------------------------
// GCN conv for stages 2/3 (unchanged from round 0).
// ---------------------------------------------------------------------------
template<int NPER, int LEVEL, bool COMPACT, bool RSUM, int NCH>
__global__ __launch_bounds__(512) void gcn_conv_k(
    float* __restrict__ h,
    const int* __restrict__ src, const int* __restrict__ dst,
    const int* __restrict__ nmap1, const int* __restrict__ nmap2,
    const float* __restrict__ bias, float* __restrict__ rsum) {
  constexpr int HALVES = 64 / NCH;
  __shared__ float agg[NPER * NCH];
  __shared__ float dinv[NPER];
  __shared__ float recip[NPER];
  __shared__ int   deg[NPER];
  __shared__ int   cnt[1];
  __shared__ int   elist[COMPACT ? EPG : 1];
  __shared__ float rs[RSUM ? 64 : 1];

  const int g = blockIdx.x;
  const int tid = threadIdx.x;
  const int lane = tid & 63, wave = tid >> 6;
  const int e0 = g * EPG;
  const size_t hbase = (size_t)g * NPER * 64;

  for (int i = tid; i < NPER; i += 512) deg[i] = 0;
  if (COMPACT && tid == 0) cnt[0] = 0;
  if (RSUM && tid < 64) rs[tid] = 0.f;
  __syncthreads();

  for (int e = tid; e < EPG; e += 512) {
    int s = src[e0 + e], d = dst[e0 + e];
    int ls = 0, ld = 0; bool valid = true;
    if (LEVEL == 0) {
      ls = s - g * NPER; ld = d - g * NPER;
    } else if (LEVEL == 1) {
      int ns = nmap1[s], nd = nmap1[d];
      valid = (ns >= 0) && (nd >= 0);
      ls = ns - g * NPER; ld = nd - g * NPER;
    } else {
      int ns = nmap1[s], nd = nmap1[d];
      if (ns >= 0 && nd >= 0) {
        int ns2 = nmap2[ns], nd2 = nmap2[nd];
        valid = (ns2 >= 0) && (nd2 >= 0);
        ls = ns2 - g * NPER; ld = nd2 - g * NPER;
      } else {
        valid = false;
      }
    }
    if (valid) {
      atomicAdd(&deg[ld], 1);
      if (COMPACT) { int p = atomicAdd(&cnt[0], 1); elist[p] = ls | (ld << 16); }
    }
  }
  __syncthreads();
  for (int i = tid; i < NPER; i += 512) {
    float df = (float)deg[i] + 1.0f;
    dinv[i]  = 1.0f / sqrtf(df);
    recip[i] = 1.0f / df;
  }
  __syncthreads();

  float part = 0.f;
  for (int half = 0; half < HALVES; ++half) {
    for (int i = tid; i < NPER * NCH; i += 512) agg[i] = 0.f;
    __syncthreads();

    if (COMPACT) {
      const int n = cnt[0];
      for (int i = wave; i < n; i += 8) {
        int pk = elist[i];
        int ls = pk & 0xFFFF, ld = pk >> 16;
        float coef = dinv[ls] * dinv[ld];
        float v = coef * h[hbase + (size_t)ls * 64 + lane];
        atomicAdd(&agg[ld * 64 + lane], v);
      }
    } else {
      const int ch = lane & 31, sub = lane >> 5;
      const int cofs = half * 32 + ch;
      for (int i2 = wave * 8; i2 < EPG / 2; i2 += 64) {
        float v[8]; int ldq[8];
#pragma unroll
        for (int qq = 0; qq < 8; ++qq) {
          int e = e0 + 2 * (i2 + qq) + sub;
          int s = src[e], d = dst[e];
          int ls = s - g * NPER;
          ldq[qq] = d - g * NPER;
          v[qq] = dinv[ls] * h[hbase + (size_t)ls * 64 + cofs];
        }
#pragma unroll
        for (int qq = 0; qq < 8; ++qq)
          atomicAdd(&agg[ldq[qq] * 32 + ch], dinv[ldq[qq]] * v[qq]);
      }
    }
    __syncthreads();

    for (int idx = tid; idx < NPER * NCH; idx += 512) {
      int i  = idx / NCH;
      int ch = idx & (NCH - 1);
      int col = half * NCH + ch;
      size_t a = hbase + (size_t)i * 64 + col;
      float u = h[a];
      float o = agg[idx] + u * recip[i] + bias[col];
      o = fmaxf(o, 0.f);
      h[a] = o;
      if (RSUM) part += o;
    }
    __syncthreads();
  }

  if (RSUM) {
    atomicAdd(&rs[tid & 63], part);
    __syncthreads();
    if (tid < 64) rsum[g * 64 + tid] = rs[tid];
  }
}

// ---------------------------------------------------------------------------
// TopK pooling (unchanged).
// ---------------------------------------------------------------------------
template<int NPER, int KK>
__global__ __launch_bounds__(512) void topk_pool_k(
    const float* __restrict__ h, const float* __restrict__ pw,
    float* __restrict__ xp, int* __restrict__ nmap, float* __restrict__ rsum) {
  __shared__ float sc[NPER];
  __shared__ int   sel[KK];
  __shared__ float rs[64];
  const int g = blockIdx.x, tid = threadIdx.x;
  const int lane = tid & 63, wave = tid >> 6;
  const size_t base = (size_t)g * NPER * 64;

  float pwl = pw[lane];
  float t = pwl * pwl;
#pragma unroll
  for (int o = 32; o; o >>= 1) t += __shfl_xor(t, o);
  const float nrm = sqrtf(t);

  for (int i = wave; i < NPER; i += 8) {
    float d = h[base + (size_t)i * 64 + lane] * pwl;
#pragma unroll
    for (int o = 32; o; o >>= 1) d += __shfl_xor(d, o);
    if (lane == 0) sc[i] = tanhf(d / nrm);
  }
  if (tid < 64) rs[tid] = 0.f;
  __syncthreads();

  if (tid < NPER) {
    float si = sc[tid];
    int r = 0;
    for (int j = 0; j < NPER; ++j) {
      float sj = sc[j];
      r += (sj > si) || (sj == si && j < tid);
    }
    nmap[g * NPER + tid] = (r < KK) ? (g * KK + r) : -1;
    if (r < KK) sel[r] = tid;
  }
  __syncthreads();

  float part = 0.f;
  for (int r = wave; r < KK; r += 8) {
    int i = sel[r];
    float s = sc[i];
    float v = h[base + (size_t)i * 64 + lane] * s;
    xp[((size_t)g * KK + r) * 64 + lane] = v;
    part += v;
  }
  atomicAdd(&rs[lane], part);
  __syncthreads();
  if (tid < 64) rsum[g * 64 + tid] = rs[tid];
}

// ---------------------------------------------------------------------------
// Final linear: out[g] = [r3|r2|r1] @ Wl + bl
// ---------------------------------------------------------------------------
__global__ __launch_bounds__(256) void final_linear(
    const float* __restrict__ r3, const float* __restrict__ r2,
    const float* __restrict__ r1, const float* __restrict__ Wl,
    const float* __restrict__ bl, float* __restrict__ out) {
  int g = threadIdx.x;
  if (g >= BGR) return;
  float a0 = bl[0], a1 = bl[1];
  for (int t = 0; t < 64; ++t) {
    float v = r3[g * 64 + t];
    a0 = fmaf(v, Wl[t * 2 + 0], a0);
    a1 = fmaf(v, Wl[t * 2 + 1], a1);
  }
  for (int t = 0; t < 64; ++t) {
    float v = r2[g * 64 + t];
    a0 = fmaf(v, Wl[(64 + t) * 2 + 0], a0);
    a1 = fmaf(v, Wl[(64 + t) * 2 + 1], a1);
  }
  for (int t = 0; t < 64; ++t) {
    float v = r1[g * 64 + t];
    a0 = fmaf(v, Wl[(128 + t) * 2 + 0], a0);
    a1 = fmaf(v, Wl[(128 + t) * 2 + 1], a1);
  }
  out[g * 2 + 0] = a0;
  out[g * 2 + 1] = a1;
}

// ---------------------------------------------------------------------------
extern "C" void kernel_launch(void* const* d_in, const int* in_sizes, int n_in,
                              void* d_out, int out_size, void* d_ws, size_t ws_size,
                              hipStream_t stream) {
  const float* x   = (const float*)d_in[0];
  const int*   src = (const int*)d_in[1];
  const int*   dst = (const int*)d_in[2];
  const float* W1  = (const float*)d_in[4];
  const float* b1  = (const float*)d_in[5];
  const float* W2  = (const float*)d_in[6];
  const float* b2  = (const float*)d_in[7];
  const float* W3  = (const float*)d_in[8];
  const float* b3  = (const float*)d_in[9];
  const float* pw1 = (const float*)d_in[10];
  const float* pw2 = (const float*)d_in[11];
  const float* Wl  = (const float*)d_in[12];
  const float* bl  = (const float*)d_in[13];
  float* out = (float*)d_out;

  float* ws    = (float*)d_ws;
  float* h1    = ws;                               // 102400*64
  float* hp1   = h1 + (size_t)102400 * 64;         // 25600*64
  int*   nmap1 = (int*)(hp1 + (size_t)25600 * 64); // 102,400
  int*   nmap2 = nmap1 + 102400;                   // 25,600
  float* r1    = (float*)(nmap2 + 25600);          // 16,384
  float* r2    = r1 + 16384;
  float* r3    = r2 + 16384;
  float* h2    = h1;                               // alias
  float* hp2   = h1 + (size_t)25600 * 64;          // alias
  float* h3    = h1 + (size_t)25600 * 64 + (size_t)6400 * 64;

  // Stage 1
  gemm64<128><<<102400 / 64, 256, 0, stream>>>(x, W1, h1);
  gcn_conv1_csr<<<dim3(4, BGR), 512, 0, stream>>>(h1, src, dst, b1);
  topk_pool_k<400, 100><<<BGR, 512, 0, stream>>>(h1, pw1, hp1, nmap1, r1);

  // Stage 2
  gemm64<64><<<25600 / 64, 256, 0, stream>>>(hp1, W2, h2);
  gcn_conv_k<100, 1, true, false, 64><<<BGR, 512, 0, stream>>>(
      h2, src, dst, nmap1, nullptr, b2, nullptr);
  topk_pool_k<100, 25><<<BGR, 512, 0, stream>>>(h2, pw2, hp2, nmap2, r2);

  // Stage 3
  gemm64<64><<<6400 / 64, 256, 0, stream>>>(hp2, W3, h3);
  gcn_conv_k<25, 2, true, true, 64><<<BGR, 512, 0, stream>>>(
      h3, src, dst, nmap1, nmap2, b3, r3);

  // Readout
  final_linear<<<1, 256, 0, stream>>>(r3, r2, r1, Wl, bl, out);
}

// Round 3
// 193.590 us; speedup vs baseline: 3.7909x; 1.4933x over previous
//
#include <hip/hip_runtime.h>
#include <hip/hip_bf16.h>
#include <math.h>

#define BGR  256      // graphs
#define NN   400      // nodes per graph (stage 1)
#define EPG  6400     // edges per graph

// ---------------------------------------------------------------------------
// GEMM: H[M x 64] = X[M x K] @ W[K x 64], M multiple of 64, f32.
// ---------------------------------------------------------------------------
template<int K>
__global__ __launch_bounds__(256) void gemm64(const float* __restrict__ X,
                                              const float* __restrict__ W,
                                              float* __restrict__ H) {
  __shared__ float xs[64][K + 8];
  const int m0 = blockIdx.x * 64;
  for (int i = threadIdx.x; i < 64 * (K / 4); i += 256) {
    int m = i / (K / 4), q = i % (K / 4);
    float4 v = *reinterpret_cast<const float4*>(X + (size_t)(m0 + m) * K + q * 4);
    *reinterpret_cast<float4*>(&xs[m][q * 4]) = v;
  }
  __syncthreads();
  const int c = threadIdx.x & 63;
  const int mg = (threadIdx.x >> 6) * 16;
  float acc[16];
#pragma unroll
  for (int i = 0; i < 16; ++i) acc[i] = 0.f;
  for (int k = 0; k < K; k += 4) {
    float w0 = W[(k + 0) * 64 + c];
    float w1 = W[(k + 1) * 64 + c];
    float w2 = W[(k + 2) * 64 + c];
    float w3 = W[(k + 3) * 64 + c];
#pragma unroll
    for (int i = 0; i < 16; ++i) {
      float4 xv = *reinterpret_cast<const float4*>(&xs[mg + i][k]);
      float a = acc[i];
      a = fmaf(xv.x, w0, a);
      a = fmaf(xv.y, w1, a);
      a = fmaf(xv.z, w2, a);
      a = fmaf(xv.w, w3, a);
      acc[i] = a;
    }
  }
#pragma unroll
  for (int i = 0; i < 16; ++i)
    H[(size_t)(m0 + mg + i) * 64 + c] = acc[i];
}

// ---------------------------------------------------------------------------
// Stage-1 conv: block (q,g) owns 16 channels of graph g. h-quarter staged in
// LDS pre-scaled by dinv[src]; CSR walk reads LDS only. Emits per-quarter
// score partials (h_post . pw) for topk1.
//   out[n] = dinv[n]*(sum_{s in N(n)} hl[s] + hl[n]) + b   (hl = dinv*h)
// ---------------------------------------------------------------------------
__global__ __launch_bounds__(512) void gcn_conv1(
    float* __restrict__ h,
    const int* __restrict__ src, const int* __restrict__ dst,
    const float* __restrict__ bias, const float* __restrict__ pw,
    float* __restrict__ score4) {
  __shared__ float          hl[NN * 17];     // padded stride 17
  __shared__ unsigned short csr[EPG];        // pre-multiplied src*17
  __shared__ int            deg[NN];
  __shared__ float          dinv[NN];
  __shared__ int            off[NN];

  const int q = blockIdx.x, g = blockIdx.y;
  const int tid = threadIdx.x;
  const int e0 = g * EPG;
  const size_t hbase = (size_t)g * NN * 64 + q * 16;

  for (int i = tid; i < NN; i += 512) deg[i] = 0;
  __syncthreads();

  // single pass over edges: keep packed (ls, ld) in registers, count degree
  int epack[13];
#pragma unroll
  for (int u = 0; u < 13; ++u) {
    int e = tid + u * 512;
    int pk = -1;
    if (e < EPG) {
      int ls = src[e0 + e] - g * NN;
      int ld = dst[e0 + e] - g * NN;
      pk = ls | (ld << 16);
      atomicAdd(&deg[ld], 1);
    }
    epack[u] = pk;
  }
  __syncthreads();

  for (int i = tid; i < NN; i += 512)
    dinv[i] = 1.0f / sqrtf((float)deg[i] + 1.0f);
  if (tid < NN) {
    int s = 0;
    for (int j = 0; j < tid; ++j) s += deg[j];
    off[tid] = s;
  }
  __syncthreads();

  // stage scaled h quarter; fill CSR from registers (off becomes end)
  for (int i = tid; i < NN * 16; i += 512) {
    int n = i >> 4, c = i & 15;
    hl[n * 17 + c] = dinv[n] * h[hbase + (size_t)n * 64 + c];
  }
#pragma unroll
  for (int u = 0; u < 13; ++u) {
    int pk = epack[u];
    if (pk != -1) {
      int p = atomicAdd(&off[pk >> 16], 1);
      csr[p] = (unsigned short)((pk & 0xFFFF) * 17);
    }
  }
  __syncthreads();

  // gather: 16-lane group per dst node
  const int grp16 = tid >> 4;                 // 0..31
  const int l16   = tid & 15;
  const int gb    = ((tid & 63) >> 4) << 4;   // group base lane in wave
  const int col   = q * 16 + l16;
  const float bcol = bias[col];
  const float pwc  = pw[col];

  for (int it = 0; it < 13; ++it) {
    int n = it * 32 + grp16;
    if (n >= NN) break;
    int end = off[n];
    int e   = end - deg[n];
    float a0 = hl[n * 17 + l16];   // self-loop term
    float a1 = 0.f, a2 = 0.f, a3 = 0.f;
    while (e + 4 <= end) {
      int my = csr[e + (l16 & 3)];
      int s0 = __shfl(my, gb + 0);
      int s1 = __shfl(my, gb + 1);
      int s2 = __shfl(my, gb + 2);
      int s3 = __shfl(my, gb + 3);
      a0 += hl[s0 + l16];
      a1 += hl[s1 + l16];
      a2 += hl[s2 + l16];
      a3 += hl[s3 + l16];
      e += 4;
    }
    for (; e < end; ++e) a0 += hl[csr[e] + l16];
    float o = fmaxf(fmaf((a0 + a1) + (a2 + a3), dinv[n], bcol), 0.f);
    h[hbase + (size_t)n * 64 + l16] = o;
    // score partial over this quarter's 16 channels
    float sd = o * pwc;
    sd += __shfl_xor(sd, 1);
    sd += __shfl_xor(sd, 2);
    sd += __shfl_xor(sd, 4);
    sd += __shfl_xor(sd, 8);
    if (l16 == 0) score4[(g * NN + n) * 4 + q] = sd;
  }
}

// ---------------------------------------------------------------------------
// TopK pooling: scores from precomputed dot partials (NS=4) or raw dot (NS=1).
// Exact lax.top_k semantics via stable rank. Deterministic r-sum.
// ---------------------------------------------------------------------------
template<int NPER, int KK, int NS>
__global__ __launch_bounds__(512) void topk_pool_k(
    const float* __restrict__ h, const float* __restrict__ scorein,
    const float* __restrict__ pw,
    float* __restrict__ xp, int* __restrict__ nmap, float* __restrict__ rsum) {
  __shared__ float sc[NPER];
  __shared__ int   sel[KK];
  __shared__ float rsw[8][64];
  __shared__ float nrm_s;
  const int g = blockIdx.x, tid = threadIdx.x;
  const int lane = tid & 63, wave = tid >> 6;
  const size_t base = (size_t)g * NPER * 64;

  if (wave == 0) {
    float pwl = pw[lane];
    float t = pwl * pwl;
#pragma unroll
    for (int o = 32; o; o >>= 1) t += __shfl_xor(t, o);
    if (lane == 0) nrm_s = sqrtf(t);
  }
  __syncthreads();

  if (tid < NPER) {
    const float* sp = scorein + (size_t)(g * NPER + tid) * NS;
    float s = 0.f;
#pragma unroll
    for (int u = 0; u < NS; ++u) s += sp[u];
    sc[tid] = tanhf(s / nrm_s);
  }
  __syncthreads();

  if (tid < NPER) {
    float si = sc[tid];
    int r = 0;
    for (int j = 0; j < NPER; ++j) {
      float sj = sc[j];
      r += (sj > si) || (sj == si && j < tid);
    }
    nmap[g * NPER + tid] = (r < KK) ? (g * KK + r) : -1;
    if (r < KK) sel[r] = tid;
  }
  __syncthreads();

  float part = 0.f;
  for (int r = wave; r < KK; r += 8) {
    int i = sel[r];
    float s = sc[i];
    float v = h[base + (size_t)i * 64 + lane] * s;
    xp[((size_t)g * KK + r) * 64 + lane] = v;
    part += v;
  }
  rsw[wave][lane] = part;
  __syncthreads();
  if (tid < 64) {
    float r0 = ((rsw[0][tid] + rsw[1][tid]) + (rsw[2][tid] + rsw[3][tid]))
             + ((rsw[4][tid] + rsw[5][tid]) + (rsw[6][tid] + rsw[7][tid]));
    rsum[g * 64 + tid] = r0;
  }
}

// ---------------------------------------------------------------------------
// Stage-2: fused gemm (hp@W2) + conv + score dot. One block per graph.
// ---------------------------------------------------------------------------
__global__ __launch_bounds__(512) void gcn_conv2(
    const float* __restrict__ hp, float* __restrict__ h2,
    const int* __restrict__ src, const int* __restrict__ dst,
    const int* __restrict__ nmap1,
    const float* __restrict__ W, const float* __restrict__ bias,
    const float* __restrict__ pw, float* __restrict__ scraw) {
  __shared__ float          Ws[64 * 64];
  __shared__ float          hl[100 * 64];
  __shared__ unsigned char  csr[EPG];
  __shared__ int            deg[100];
  __shared__ float          dinv[100];
  __shared__ int            off[100];
  const int g = blockIdx.x, tid = threadIdx.x;
  const int lane = tid & 63, wave = tid >> 6;
  const int e0 = g * EPG, n0 = g * 100;

  for (int i = tid; i < 4096; i += 512) Ws[i] = W[i];
  if (tid < 100) deg[tid] = 0;
  __syncthreads();

  int epack[13];
#pragma unroll
  for (int u = 0; u < 13; ++u) {
    int e = tid + u * 512;
    int pk = -1;
    if (e < EPG) {
      int ns = nmap1[src[e0 + e]], nd = nmap1[dst[e0 + e]];
      if ((ns | nd) >= 0) {
        int ls = ns - n0, ld = nd - n0;
        pk = ls | (ld << 16);
        atomicAdd(&deg[ld], 1);
      }
    }
    epack[u] = pk;
  }
  __syncthreads();

  if (tid < 100) {
    dinv[tid] = 1.0f / sqrtf((float)deg[tid] + 1.0f);
    int s = 0;
    for (int j = 0; j < tid; ++j) s += deg[j];
    off[tid] = s;
  }
  __syncthreads();

  // matmul + scale into hl (pairs of nodes share the Ws read)
  for (int n = wave; n < 100; n += 16) {
    int n2 = n + 8;
    float rv  = hp[(size_t)(n0 + n) * 64 + lane];
    float rv2 = (n2 < 100) ? hp[(size_t)(n0 + n2) * 64 + lane] : 0.f;
    float a = 0.f, a2 = 0.f;
#pragma unroll
    for (int k = 0; k < 64; ++k) {
      float w = Ws[k * 64 + lane];
      a  = fmaf(__shfl(rv,  k), w, a);
      a2 = fmaf(__shfl(rv2, k), w, a2);
    }
    hl[n * 64 + lane] = dinv[n] * a;
    if (n2 < 100) hl[n2 * 64 + lane] = dinv[n2] * a2;
  }
#pragma unroll
  for (int u = 0; u < 13; ++u) {
    int pk = epack[u];
    if (pk != -1) {
      int p = atomicAdd(&off[pk >> 16], 1);
      csr[p] = (unsigned char)(pk & 0xFFFF);
    }
  }
  __syncthreads();

  const float bcol = bias[lane], pwc = pw[lane];
  for (int n = wave; n < 100; n += 8) {
    int end = off[n], e = end - deg[n];
    float a0 = hl[n * 64 + lane], a1 = 0.f;
    for (; e + 1 < end; e += 2) {
      a0 += hl[csr[e] * 64 + lane];
      a1 += hl[csr[e + 1] * 64 + lane];
    }
    if (e < end) a0 += hl[csr[e] * 64 + lane];
    float o = fmaxf(fmaf(a0 + a1, dinv[n], bcol), 0.f);
    h2[(size_t)(n0 + n) * 64 + lane] = o;
    float sd = o * pwc;
#pragma unroll
    for (int o2 = 32; o2; o2 >>= 1) sd += __shfl_xor(sd, o2);
    if (lane == 0) scraw[n0 + n] = sd;
  }
}

// ---------------------------------------------------------------------------
// Stage-3: fused gemm (hp@W3) + conv + r3 column-sum + final linear.
// ---------------------------------------------------------------------------
__global__ __launch_bounds__(512) void gcn_conv3_final(
    const float* __restrict__ hp,
    const int* __restrict__ src, const int* __restrict__ dst,
    const int* __restrict__ nmap1, const int* __restrict__ nmap2,
    const float* __restrict__ W, const float* __restrict__ bias,
    const float* __restrict__ r1, const float* __restrict__ r2,
    const float* __restrict__ Wl, const float* __restrict__ bl,
    float* __restrict__ out) {
  __shared__ float          Ws[64 * 64];
  __shared__ float          hl[25 * 64];
  __shared__ unsigned char  csr[EPG];
  __shared__ int            deg[25];
  __shared__ float          dinv[25];
  __shared__ int            off[25];
  __shared__ float          rsw[8][64];
  const int g = blockIdx.x, tid = threadIdx.x;
  const int lane = tid & 63, wave = tid >> 6;
  const int e0 = g * EPG, n0 = g * 25;

  for (int i = tid; i < 4096; i += 512) Ws[i] = W[i];
  if (tid < 25) deg[tid] = 0;
  __syncthreads();

  int epack[13];
#pragma unroll
  for (int u = 0; u < 13; ++u) {
    int e = tid + u * 512;
    int pk = -1;
    if (e < EPG) {
      int ns = nmap1[src[e0 + e]], nd = nmap1[dst[e0 + e]];
      if ((ns | nd) >= 0) {
        int ns2 = nmap2[ns], nd2 = nmap2[nd];
        if ((ns2 | nd2) >= 0) {
          int ls = ns2 - n0, ld = nd2 - n0;
          pk = ls | (ld << 16);
          atomicAdd(&deg[ld], 1);
        }
      }
    }
    epack[u] = pk;
  }
  __syncthreads();

  if (tid < 25) {
    dinv[tid] = 1.0f / sqrtf((float)deg[tid] + 1.0f);
    int s = 0;
    for (int j = 0; j < tid; ++j) s += deg[j];
    off[tid] = s;
  }
  __syncthreads();

  for (int n = wave; n < 25; n += 16) {
    int n2 = n + 8;
    float rv  = hp[(size_t)(n0 + n) * 64 + lane];
    float rv2 = (n2 < 25) ? hp[(size_t)(n0 + n2) * 64 + lane] : 0.f;
    float a = 0.f, a2 = 0.f;
#pragma unroll
    for (int k = 0; k < 64; ++k) {
      float w = Ws[k * 64 + lane];
      a  = fmaf(__shfl(rv,  k), w, a);
      a2 = fmaf(__shfl(rv2, k), w, a2);
    }
    hl[n * 64 + lane] = dinv[n] * a;
    if (n2 < 25) hl[n2 * 64 + lane] = dinv[n2] * a2;
  }
#pragma unroll
  for (int u = 0; u < 13; ++u) {
    int pk = epack[u];
    if (pk != -1) {
      int p = atomicAdd(&off[pk >> 16], 1);
      csr[p] = (unsigned char)(pk & 0xFFFF);
    }
  }
  __syncthreads();

  const float bcol = bias[lane];
  float part = 0.f;
  for (int n = wave; n < 25; n += 8) {
    int end = off[n], e = end - deg[n];
    float a0 = hl[n * 64 + lane], a1 = 0.f;
    for (; e + 1 < end; e += 2) {
      a0 += hl[csr[e] * 64 + lane];
      a1 += hl[csr[e + 1] * 64 + lane];
    }
    if (e < end) a0 += hl[csr[e] * 64 + lane];
    part += fmaxf(fmaf(a0 + a1, dinv[n], bcol), 0.f);
  }
  rsw[wave][lane] = part;
  __syncthreads();

  if (tid < 64) {
    float r3c = ((rsw[0][tid] + rsw[1][tid]) + (rsw[2][tid] + rsw[3][tid]))
              + ((rsw[4][tid] + rsw[5][tid]) + (rsw[6][tid] + rsw[7][tid]));
    float f1 = r2[g * 64 + tid];
    float f2 = r1[g * 64 + tid];
    float p0 = r3c * Wl[tid * 2 + 0] + f1 * Wl[(64 + tid) * 2 + 0] + f2 * Wl[(128 + tid) * 2 + 0];
    float p1 = r3c * Wl[tid * 2 + 1] + f1 * Wl[(64 + tid) * 2 + 1] + f2 * Wl[(128 + tid) * 2 + 1];
#pragma unroll
    for (int o = 32; o; o >>= 1) {
      p0 += __shfl_xor(p0, o);
      p1 += __shfl_xor(p1, o);
    }
    if (tid == 0) {
      out[g * 2 + 0] = p0 + bl[0];
      out[g * 2 + 1] = p1 + bl[1];
    }
  }
}

// ---------------------------------------------------------------------------
extern "C" void kernel_launch(void* const* d_in, const int* in_sizes, int n_in,
                              void* d_out, int out_size, void* d_ws, size_t ws_size,
                              hipStream_t stream) {
  const float* x   = (const float*)d_in[0];
  const int*   src = (const int*)d_in[1];
  const int*   dst = (const int*)d_in[2];
  const float* W1  = (const float*)d_in[4];
  const float* b1  = (const float*)d_in[5];
  const float* W2  = (const float*)d_in[6];
  const float* b2  = (const float*)d_in[7];
  const float* W3  = (const float*)d_in[8];
  const float* b3  = (const float*)d_in[9];
  const float* pw1 = (const float*)d_in[10];
  const float* pw2 = (const float*)d_in[11];
  const float* Wl  = (const float*)d_in[12];
  const float* bl  = (const float*)d_in[13];
  float* out = (float*)d_out;

  float* ws     = (float*)d_ws;
  float* h1     = ws;                                   // 102400*64
  float* score4 = h1 + (size_t)102400 * 64;             // 102400*4
  float* hp1    = score4 + (size_t)102400 * 4;          // 25600*64
  int*   nmap1  = (int*)(hp1 + (size_t)25600 * 64);     // 102400
  int*   nmap2  = nmap1 + 102400;                       // 25600
  float* sc2    = (float*)(nmap2 + 25600);              // 25600
  float* r1     = sc2 + 25600;                          // 16384
  float* r2     = r1 + 16384;                           // 16384
  float* h2     = h1;                                   // alias (h1 dead after topk1)
  float* hp2    = h1 + (size_t)25600 * 64;              // alias, disjoint from h2 rows

  // Stage 1
  gemm64<128><<<102400 / 64, 256, 0, stream>>>(x, W1, h1);
  gcn_conv1<<<dim3(4, BGR), 512, 0, stream>>>(h1, src, dst, b1, pw1, score4);
  topk_pool_k<400, 100, 4><<<BGR, 512, 0, stream>>>(h1, score4, pw1, hp1, nmap1, r1);

  // Stage 2 (gemm fused)
  gcn_conv2<<<BGR, 512, 0, stream>>>(hp1, h2, src, dst, nmap1, W2, b2, pw2, sc2);
  topk_pool_k<100, 25, 1><<<BGR, 512, 0, stream>>>(h2, sc2, pw2, hp2, nmap2, r2);

  // Stage 3 (gemm + r3 + final linear fused)
  gcn_conv3_final<<<BGR, 512, 0, stream>>>(hp2, src, dst, nmap1, nmap2,
                                           W3, b3, r1, r2, Wl, bl, out);
}